// Round 4
// baseline (1590.266 us; speedup 1.0000x reference)
//
#include <hip/hip_runtime.h>
#include <cfloat>
#include <cmath>

#define NROWS 16384
#define DDIM  4096
#define NEXP  64
#define TOPK  8
#define GAP_THRESH 5e-4f

#define KSPLIT 4
#define KPB    (DDIM / KSPLIT)   // 1024 k per block
#define CHUNK  32                // k per LDS chunk
#define NCHUNK (KPB / CHUNK)     // 32
#define RB     128               // rows per block

// ---------------------------------------------------------------------------
// ws layout: [Wd 2MB][count 256B][list 64KB][part 16MB]
// ---------------------------------------------------------------------------

__global__ __launch_bounds__(256) void prep_kernel(const float* __restrict__ W,
                                                   double* __restrict__ Wd,
                                                   int* __restrict__ count) {
    int t = blockIdx.x * 256 + threadIdx.x;
    Wd[t] = (double)W[t];
    if (t == 0) *count = 0;
}

// ---------------------------------------------------------------------------
// Gate GEMM: fp32, LDS-transposed double-buffered tiles, 128 rows x 64 experts
// per block, K-split 4.  Thread = 8 rows x 4 experts.  XOR swizzle
// (idx ^ ((k>>2)&7)<<3) makes both staging writes and b128 reads ~2-way.
// ---------------------------------------------------------------------------
__global__ __launch_bounds__(256, 2) void gate_kernel(
    const float* __restrict__ x,
    const float* __restrict__ W,
    float* __restrict__ part)          // [KSPLIT][NROWS][NEXP]
{
    __shared__ float xT[2][CHUNK][RB];    // 32 KB
    __shared__ float wT[2][CHUNK][NEXP];  // 16 KB

    const int t    = threadIdx.x;
    const int h    = blockIdx.x & (KSPLIT - 1);
    const int rb   = blockIdx.x >> 2;
    const int row0 = rb * RB;
    const int k0   = h * KPB;

    const int rg  = t & 15;      // row-group: rows rg*4..+3 and 64+rg*4..+3
    const int eg  = t >> 4;      // expert-group: experts eg*4..+3
    const int e0  = eg * 4;
    const int rg4 = rg * 4;

    // staging mapping: thread covers (row = t>>3 + 32j, k4 = t&7)
    const int sk4 = t & 7;
    const int sr0 = t >> 3;

    const float* xg = x + (size_t)(row0 + sr0) * DDIM + k0 + sk4 * 4;
    const float* wg = W + (size_t)sr0 * DDIM + k0 + sk4 * 4;

    float acc[2][4][4] = {};
    float4 gx[4], gw[2];

    // ---- prologue: stage chunk 0 ------------------------------------------
#pragma unroll
    for (int j = 0; j < 4; ++j)
        gx[j] = *reinterpret_cast<const float4*>(xg + (size_t)j * 32 * DDIM);
#pragma unroll
    for (int j = 0; j < 2; ++j)
        gw[j] = *reinterpret_cast<const float4*>(wg + (size_t)j * 32 * DDIM);
#pragma unroll
    for (int j = 0; j < 4; ++j) {
        const int rw = (sr0 + 32 * j) ^ (sk4 << 3);
        const float v[4] = {gx[j].x, gx[j].y, gx[j].z, gx[j].w};
#pragma unroll
        for (int c4 = 0; c4 < 4; ++c4) xT[0][sk4 * 4 + c4][rw] = v[c4];
    }
#pragma unroll
    for (int j = 0; j < 2; ++j) {
        const int ew = (sr0 + 32 * j) ^ (sk4 << 3);
        const float v[4] = {gw[j].x, gw[j].y, gw[j].z, gw[j].w};
#pragma unroll
        for (int c4 = 0; c4 < 4; ++c4) wT[0][sk4 * 4 + c4][ew] = v[c4];
    }
    __syncthreads();

    // ---- main loop --------------------------------------------------------
    for (int c = 0; c < NCHUNK; ++c) {
        const int buf = c & 1;

        if (c + 1 < NCHUNK) {   // issue next-chunk global loads (hide HBM)
            const int ko = (c + 1) * CHUNK;
#pragma unroll
            for (int j = 0; j < 4; ++j)
                gx[j] = *reinterpret_cast<const float4*>(xg + (size_t)j * 32 * DDIM + ko);
#pragma unroll
            for (int j = 0; j < 2; ++j)
                gw[j] = *reinterpret_cast<const float4*>(wg + (size_t)j * 32 * DDIM + ko);
        }

        const float* xb_ = &xT[buf][0][0];
        const float* wb_ = &wT[buf][0][0];
        int xo[8], wo[8];
#pragma unroll
        for (int q = 0; q < 8; ++q) { xo[q] = rg4 ^ (q << 3); wo[q] = e0 ^ (q << 3); }

#pragma unroll
        for (int k = 0; k < CHUNK; ++k) {
            const int q = (k >> 2) & 7;                       // compile-time
            float4 xa = *reinterpret_cast<const float4*>(xb_ + k * RB + xo[q]);
            float4 xc = *reinterpret_cast<const float4*>(xb_ + k * RB + xo[q] + 64);
            float4 wv = *reinterpret_cast<const float4*>(wb_ + k * NEXP + wo[q]);
            const float xav[4] = {xa.x, xa.y, xa.z, xa.w};
            const float xcv[4] = {xc.x, xc.y, xc.z, xc.w};
            const float wvv[4] = {wv.x, wv.y, wv.z, wv.w};
#pragma unroll
            for (int ri = 0; ri < 4; ++ri)
#pragma unroll
                for (int ei = 0; ei < 4; ++ei) {
                    acc[0][ri][ei] = fmaf(xav[ri], wvv[ei], acc[0][ri][ei]);
                    acc[1][ri][ei] = fmaf(xcv[ri], wvv[ei], acc[1][ri][ei]);
                }
        }
        __syncthreads();

        if (c + 1 < NCHUNK) {   // write prefetched data into the other buffer
            const int nb = buf ^ 1;
#pragma unroll
            for (int j = 0; j < 4; ++j) {
                const int rw = (sr0 + 32 * j) ^ (sk4 << 3);
                const float v[4] = {gx[j].x, gx[j].y, gx[j].z, gx[j].w};
#pragma unroll
                for (int c4 = 0; c4 < 4; ++c4) xT[nb][sk4 * 4 + c4][rw] = v[c4];
            }
#pragma unroll
            for (int j = 0; j < 2; ++j) {
                const int ew = (sr0 + 32 * j) ^ (sk4 << 3);
                const float v[4] = {gw[j].x, gw[j].y, gw[j].z, gw[j].w};
#pragma unroll
                for (int c4 = 0; c4 < 4; ++c4) wT[nb][sk4 * 4 + c4][ew] = v[c4];
            }
        }
        __syncthreads();
    }

    // ---- store partials (float4, coalesced within e-groups) ---------------
#pragma unroll
    for (int half = 0; half < 2; ++half)
#pragma unroll
        for (int ri = 0; ri < 4; ++ri) {
            const int row = row0 + half * 64 + rg4 + ri;
            float4 v = make_float4(acc[half][ri][0], acc[half][ri][1],
                                   acc[half][ri][2], acc[half][ri][3]);
            *reinterpret_cast<float4*>(part + ((size_t)h * NROWS + row) * NEXP + e0) = v;
        }
}

// ---------------------------------------------------------------------------
// Reduce + top-9 + sparse softmax + ambiguity flag.  One wave per row,
// lane = expert.  (Epilogue logic proven correct in round 3.)
// ---------------------------------------------------------------------------
__global__ __launch_bounds__(256) void reduce_kernel(
    const float* __restrict__ part,
    const float* __restrict__ b,
    float* __restrict__ outp,    // [N, 64]
    float* __restrict__ outi,    // [N, 8]
    int*   __restrict__ count,
    int*   __restrict__ list)
{
    const int lane = threadIdx.x & 63;
    const int w    = threadIdx.x >> 6;
    const int row  = blockIdx.x * 4 + w;

    float orig = b[lane];
#pragma unroll
    for (int h = 0; h < KSPLIT; ++h)
        orig += part[((size_t)h * NROWS + row) * NEXP + lane];

    float cur = orig;
    float vals[9];
    float myidxf = 0.0f;
    bool  sel = false;

#pragma unroll
    for (int i = 0; i < 9; ++i) {
        float m = cur;
#pragma unroll
        for (int off = 32; off > 0; off >>= 1)
            m = fmaxf(m, __shfl_xor(m, off, 64));
        unsigned long long msk = __ballot(cur == m);
        int il = __ffsll((long long)msk) - 1;
        vals[i] = m;
        if (lane == il) { cur = -FLT_MAX; if (i < TOPK) sel = true; }
        if (i < TOPK && lane == i) myidxf = (float)il;
    }

    float ssum = 0.0f;
#pragma unroll
    for (int i = 0; i < TOPK; ++i) ssum += expf(vals[i] - vals[0]);
    float p = sel ? (expf(orig - vals[0]) / ssum) : 0.0f;

    outp[(size_t)row * NEXP + lane] = p;
    if (lane < TOPK) outi[(size_t)row * TOPK + lane] = myidxf;

    float mingap = FLT_MAX;
#pragma unroll
    for (int i = 0; i < 8; ++i) mingap = fminf(mingap, vals[i] - vals[i + 1]);
    if (lane == 0 && mingap < GAP_THRESH) {
        int pos = atomicAdd(count, 1);
        if (pos < NROWS) list[pos] = row;
    }
}

// ---------------------------------------------------------------------------
// fp64 rescue for flagged rows (proven in round 3).
// ---------------------------------------------------------------------------
__global__ __launch_bounds__(64) void fix_kernel(
    const float*  __restrict__ x,
    const double* __restrict__ Wd,
    const float*  __restrict__ b,
    float* __restrict__ outp,
    float* __restrict__ outi,
    const int* __restrict__ count,
    const int* __restrict__ list)
{
    const int lane = threadIdx.x;
    const int cnt  = *count;

    for (int i = blockIdx.x; i < cnt; i += gridDim.x) {
        const int row = list[i];
        const float*  xr = x  + (size_t)row  * DDIM;
        const double* wp = Wd + (size_t)lane * DDIM;

        double a0 = 0.0, a1 = 0.0, a2 = 0.0, a3 = 0.0;
        for (int k = 0; k < DDIM; k += 4) {
            a0 = fma((double)xr[k + 0], wp[k + 0], a0);
            a1 = fma((double)xr[k + 1], wp[k + 1], a1);
            a2 = fma((double)xr[k + 2], wp[k + 2], a2);
            a3 = fma((double)xr[k + 3], wp[k + 3], a3);
        }
        const double orig = ((a0 + a1) + (a2 + a3)) + (double)b[lane];
        double cur = orig;

        double vals[TOPK];
        float  myidxf = 0.0f;
        bool   sel = false;

#pragma unroll
        for (int tt = 0; tt < TOPK; ++tt) {
            double m = cur;
#pragma unroll
            for (int off = 32; off > 0; off >>= 1) {
                double o = __shfl_xor(m, off, 64);
                m = fmax(m, o);
            }
            unsigned long long msk = __ballot(cur == m);
            int il = __ffsll((long long)msk) - 1;
            vals[tt] = m;
            if (lane == il) { cur = -DBL_MAX; sel = true; }
            if (lane == tt)  myidxf = (float)il;
        }

        double ssum = 0.0;
#pragma unroll
        for (int tt = 0; tt < TOPK; ++tt) ssum += exp(vals[tt] - vals[0]);
        float p = sel ? (float)(exp(orig - vals[0]) / ssum) : 0.0f;

        outp[(size_t)row * NEXP + lane] = p;
        if (lane < TOPK) outi[(size_t)row * TOPK + lane] = myidxf;
    }
}

// ---------------------------------------------------------------------------
// Fallback (tiny ws): per-thread-row full fp64 from f32 W.  Correct, slow.
// ---------------------------------------------------------------------------
__global__ __launch_bounds__(64) void fallback_kernel(
    const float* __restrict__ x,
    const float* __restrict__ W,
    const float* __restrict__ b,
    float* __restrict__ outp,
    float* __restrict__ outi)
{
    const int row = blockIdx.x * 64 + threadIdx.x;
    double lg[64];
#pragma unroll
    for (int e = 0; e < 64; ++e) lg[e] = (double)b[e];
    const float* xr = x + (size_t)row * DDIM;
    for (int k = 0; k < DDIM; k += 4) {
        float4 xa = *reinterpret_cast<const float4*>(xr + k);
        double xd[4] = {(double)xa.x, (double)xa.y, (double)xa.z, (double)xa.w};
#pragma unroll
        for (int e = 0; e < 64; ++e) {
            const float* wp = W + (size_t)e * DDIM + k;
            double a = lg[e];
#pragma unroll
            for (int j = 0; j < 4; ++j) a = fma(xd[j], (double)wp[j], a);
            lg[e] = a;
        }
    }
    unsigned long long selm = 0ull;
    double vals[TOPK]; int idx[TOPK];
#pragma unroll
    for (int i = 0; i < TOPK; ++i) {
        double m = -DBL_MAX; int mi = 0;
#pragma unroll
        for (int e = 0; e < 64; ++e) {
            bool gt = !((selm >> e) & 1ull) && (lg[e] > m);
            m = gt ? lg[e] : m; mi = gt ? e : mi;
        }
        vals[i] = m; idx[i] = mi; selm |= (1ull << mi);
    }
    double ssum = 0.0;
#pragma unroll
    for (int i = 0; i < TOPK; ++i) ssum += exp(vals[i] - vals[0]);
    double inv = 1.0 / ssum;
#pragma unroll
    for (int e = 0; e < 64; ++e)
        outp[(size_t)row * NEXP + e] =
            ((selm >> e) & 1ull) ? (float)(exp(lg[e] - vals[0]) * inv) : 0.0f;
#pragma unroll
    for (int i = 0; i < TOPK; ++i)
        outi[(size_t)row * TOPK + i] = (float)idx[i];
}

// ---------------------------------------------------------------------------
extern "C" void kernel_launch(void* const* d_in, const int* in_sizes, int n_in,
                              void* d_out, int out_size, void* d_ws, size_t ws_size,
                              hipStream_t stream) {
    (void)in_sizes; (void)n_in; (void)out_size;
    const float* x = (const float*)d_in[0];
    const float* W = (const float*)d_in[1];
    const float* b = (const float*)d_in[2];

    float* outp = (float*)d_out;
    float* outi = outp + (size_t)NROWS * NEXP;

    const size_t wd_bytes  = sizeof(double) * (size_t)NEXP * DDIM;          // 2 MB
    const size_t cnt_off   = wd_bytes;
    const size_t list_off  = cnt_off + 256;
    const size_t part_off  = list_off + (size_t)NROWS * sizeof(int);
    const size_t need      = part_off + (size_t)KSPLIT * NROWS * NEXP * sizeof(float);

    if (ws_size >= need) {
        double* Wd   = (double*)d_ws;
        int*    cnt  = (int*)((char*)d_ws + cnt_off);
        int*    list = (int*)((char*)d_ws + list_off);
        float*  part = (float*)((char*)d_ws + part_off);

        prep_kernel<<<(NEXP * DDIM) / 256, 256, 0, stream>>>(W, Wd, cnt);
        gate_kernel<<<(NROWS / RB) * KSPLIT, 256, 0, stream>>>(x, W, part);
        reduce_kernel<<<NROWS / 4, 256, 0, stream>>>(part, b, outp, outi, cnt, list);
        fix_kernel<<<1024, 64, 0, stream>>>(x, Wd, b, outp, outi, cnt, list);
    } else {
        fallback_kernel<<<NROWS / 64, 64, 0, stream>>>(x, W, b, outp, outi);
    }
}

// Round 5
// 346.898 us; speedup vs baseline: 4.5842x; 4.5842x over previous
//
#include <hip/hip_runtime.h>
#include <cfloat>
#include <cmath>

#define NROWS 16384
#define DDIM  4096
#define NEXP  64
#define TOPK  8
#define GAP_THRESH 5e-4f

#define KSPLIT 4
#define KPB    (DDIM / KSPLIT)   // 1024 k per block
#define CHUNK  32                // k per LDS chunk
#define NCHUNK (KPB / CHUNK)     // 32
#define RB     128               // rows per block

// ws layout: [Wd 2MB][count 256B][list 64KB][part 16MB]

__global__ __launch_bounds__(256) void prep_kernel(const float* __restrict__ W,
                                                   double* __restrict__ Wd,
                                                   int* __restrict__ count) {
    int t = blockIdx.x * 256 + threadIdx.x;
    Wd[t] = (double)W[t];
    if (t == 0) *count = 0;
}

// async 16B global->LDS (no VGPR round-trip; LDS dest = wave-uniform base + lane*16)
__device__ __forceinline__ void gload_lds16(const float* g, float* l) {
    __builtin_amdgcn_global_load_lds(
        (const __attribute__((address_space(1))) unsigned int*)g,
        (__attribute__((address_space(3))) unsigned int*)l,
        16, 0, 0);
}

// ---------------------------------------------------------------------------
// Gate GEMM, fp32.  Tile: 128 rows x 64 experts x 1024 k.  Thread = 4 rows x
// 8 experts (dot-product along k => x and W stage LINEARLY, as required by
// global_load_lds).  x LDS tile XOR-swizzled via pre-swizzled GLOBAL source
// (rule #21: same involution on source and read; dest stays linear).
// One __syncthreads per 32-k chunk; its implicit vmcnt(0) drains the
// prefetch issued at the top of the iteration (2-phase T3-minimum).
// ---------------------------------------------------------------------------
__global__ __launch_bounds__(256, 2) void gate_kernel(
    const float* __restrict__ x,
    const float* __restrict__ W,
    float* __restrict__ part)          // [KSPLIT][NROWS][NEXP]
{
    __shared__ float xT[2][CHUNK * RB];    // 2 x 16 KB   [row][slot*4+j]
    __shared__ float wT[2][CHUNK * NEXP];  // 2 x  8 KB   [e][k4*4+j]

    const int t    = threadIdx.x;
    const int lane = t & 63;
    const int wv   = t >> 6;                 // wave id 0..3 (uniform in wave)
    const int h    = blockIdx.x & (KSPLIT - 1);
    const int row0 = (blockIdx.x >> 2) * RB;
    const int k0   = h * KPB;

    // staging source pointers (per-lane).  x source column is pre-swizzled:
    // LDS slot s of row r holds global col-group (s ^ (r&7)).
    const int l8   = lane >> 3;              // row-within-8 / expert-within-8
    const int sl   = lane & 7;               // 16B slot
    const int xcol = (sl ^ (l8 & 7)) * 4;    // swizzled float col within chunk

    const float* gx[4];
#pragma unroll
    for (int i = 0; i < 4; ++i)
        gx[i] = x + (size_t)(row0 + (wv * 4 + i) * 8 + l8) * DDIM + k0 + xcol;
    const float* gw[2];
#pragma unroll
    for (int i = 0; i < 2; ++i)
        gw[i] = W + (size_t)((wv * 2 + i) * 8 + l8) * DDIM + k0 + sl * 4;

#define STAGE(nb, c) do {                                            \
        const int koff_ = (c) * CHUNK;                               \
        _Pragma("unroll")                                            \
        for (int i_ = 0; i_ < 4; ++i_)                               \
            gload_lds16(gx[i_] + koff_, &xT[nb][(wv * 4 + i_) * 256]); \
        _Pragma("unroll")                                            \
        for (int i_ = 0; i_ < 2; ++i_)                               \
            gload_lds16(gw[i_] + koff_, &wT[nb][(wv * 2 + i_) * 256]); \
    } while (0)

    // compute-side thread tile: rows tr+32*ri, experts tc+8*ei
    const int tr = t & 31;
    const int tc = t >> 5;
    const int xsw = tr & 7;                  // read-side XOR (matches source)

    float acc[4][8] = {};

    STAGE(0, 0);
    __syncthreads();                          // drains vmcnt(0)

    int buf = 0;
    for (int c = 0; c < NCHUNK; ++c) {
        if (c + 1 < NCHUNK) STAGE(buf ^ 1, c + 1);   // async, 0 registers held

        const float* xb = xT[buf];
        const float* wb = wT[buf];
#pragma unroll
        for (int q = 0; q < 8; ++q) {                 // 4 k per quad
            float4 wv4[8];
#pragma unroll
            for (int ei = 0; ei < 8; ++ei)
                wv4[ei] = *reinterpret_cast<const float4*>(
                    wb + (tc + 8 * ei) * 32 + q * 4);
#pragma unroll
            for (int ri = 0; ri < 4; ++ri) {
                const int row = tr + 32 * ri;
                float4 xv = *reinterpret_cast<const float4*>(
                    xb + row * 32 + ((q ^ xsw) << 2));
#pragma unroll
                for (int ei = 0; ei < 8; ++ei) {
                    acc[ri][ei] = fmaf(xv.x, wv4[ei].x, acc[ri][ei]);
                    acc[ri][ei] = fmaf(xv.y, wv4[ei].y, acc[ri][ei]);
                    acc[ri][ei] = fmaf(xv.z, wv4[ei].z, acc[ri][ei]);
                    acc[ri][ei] = fmaf(xv.w, wv4[ei].w, acc[ri][ei]);
                }
            }
        }
        __syncthreads();                      // vmcnt(0) + barrier: next buf ready
        buf ^= 1;
    }
#undef STAGE

#pragma unroll
    for (int ri = 0; ri < 4; ++ri) {
        const int row = row0 + tr + 32 * ri;
        float* pp = part + ((size_t)h * NROWS + row) * NEXP + tc;
#pragma unroll
        for (int ei = 0; ei < 8; ++ei) pp[ei * 8] = acc[ri][ei];
    }
}

// ---------------------------------------------------------------------------
// Reduce + top-9 + sparse softmax + ambiguity flag (proven rounds 3-4).
// ---------------------------------------------------------------------------
__global__ __launch_bounds__(256) void reduce_kernel(
    const float* __restrict__ part,
    const float* __restrict__ b,
    float* __restrict__ outp,
    float* __restrict__ outi,
    int*   __restrict__ count,
    int*   __restrict__ list)
{
    const int lane = threadIdx.x & 63;
    const int w    = threadIdx.x >> 6;
    const int row  = blockIdx.x * 4 + w;

    float orig = b[lane];
#pragma unroll
    for (int h = 0; h < KSPLIT; ++h)
        orig += part[((size_t)h * NROWS + row) * NEXP + lane];

    float cur = orig;
    float vals[9];
    float myidxf = 0.0f;
    bool  sel = false;

#pragma unroll
    for (int i = 0; i < 9; ++i) {
        float m = cur;
#pragma unroll
        for (int off = 32; off > 0; off >>= 1)
            m = fmaxf(m, __shfl_xor(m, off, 64));
        unsigned long long msk = __ballot(cur == m);
        int il = __ffsll((long long)msk) - 1;
        vals[i] = m;
        if (lane == il) { cur = -FLT_MAX; if (i < TOPK) sel = true; }
        if (i < TOPK && lane == i) myidxf = (float)il;
    }

    float ssum = 0.0f;
#pragma unroll
    for (int i = 0; i < TOPK; ++i) ssum += expf(vals[i] - vals[0]);
    float p = sel ? (expf(orig - vals[0]) / ssum) : 0.0f;

    outp[(size_t)row * NEXP + lane] = p;
    if (lane < TOPK) outi[(size_t)row * TOPK + lane] = myidxf;

    float mingap = FLT_MAX;
#pragma unroll
    for (int i = 0; i < 8; ++i) mingap = fminf(mingap, vals[i] - vals[i + 1]);
    if (lane == 0 && mingap < GAP_THRESH) {
        int pos = atomicAdd(count, 1);
        if (pos < NROWS) list[pos] = row;
    }
}

// ---------------------------------------------------------------------------
// fp64 rescue for flagged rows (proven rounds 3-4).
// ---------------------------------------------------------------------------
__global__ __launch_bounds__(64) void fix_kernel(
    const float*  __restrict__ x,
    const double* __restrict__ Wd,
    const float*  __restrict__ b,
    float* __restrict__ outp,
    float* __restrict__ outi,
    const int* __restrict__ count,
    const int* __restrict__ list)
{
    const int lane = threadIdx.x;
    const int cnt  = *count;

    for (int i = blockIdx.x; i < cnt; i += gridDim.x) {
        const int row = list[i];
        const float*  xr = x  + (size_t)row  * DDIM;
        const double* wp = Wd + (size_t)lane * DDIM;

        double a0 = 0.0, a1 = 0.0, a2 = 0.0, a3 = 0.0;
        for (int k = 0; k < DDIM; k += 4) {
            a0 = fma((double)xr[k + 0], wp[k + 0], a0);
            a1 = fma((double)xr[k + 1], wp[k + 1], a1);
            a2 = fma((double)xr[k + 2], wp[k + 2], a2);
            a3 = fma((double)xr[k + 3], wp[k + 3], a3);
        }
        const double orig = ((a0 + a1) + (a2 + a3)) + (double)b[lane];
        double cur = orig;

        double vals[TOPK];
        float  myidxf = 0.0f;
        bool   sel = false;

#pragma unroll
        for (int tt = 0; tt < TOPK; ++tt) {
            double m = cur;
#pragma unroll
            for (int off = 32; off > 0; off >>= 1) {
                double o = __shfl_xor(m, off, 64);
                m = fmax(m, o);
            }
            unsigned long long msk = __ballot(cur == m);
            int il = __ffsll((long long)msk) - 1;
            vals[tt] = m;
            if (lane == il) { cur = -DBL_MAX; sel = true; }
            if (lane == tt)  myidxf = (float)il;
        }

        double ssum = 0.0;
#pragma unroll
        for (int tt = 0; tt < TOPK; ++tt) ssum += exp(vals[tt] - vals[0]);
        float p = sel ? (float)(exp(orig - vals[0]) / ssum) : 0.0f;

        outp[(size_t)row * NEXP + lane] = p;
        if (lane < TOPK) outi[(size_t)row * TOPK + lane] = myidxf;
    }
}

// ---------------------------------------------------------------------------
// Fallback (tiny ws): per-thread-row full fp64 from f32 W.  Correct, slow.
// ---------------------------------------------------------------------------
__global__ __launch_bounds__(64) void fallback_kernel(
    const float* __restrict__ x,
    const float* __restrict__ W,
    const float* __restrict__ b,
    float* __restrict__ outp,
    float* __restrict__ outi)
{
    const int row = blockIdx.x * 64 + threadIdx.x;
    double lg[64];
#pragma unroll
    for (int e = 0; e < 64; ++e) lg[e] = (double)b[e];
    const float* xr = x + (size_t)row * DDIM;
    for (int k = 0; k < DDIM; k += 4) {
        float4 xa = *reinterpret_cast<const float4*>(xr + k);
        double xd[4] = {(double)xa.x, (double)xa.y, (double)xa.z, (double)xa.w};
#pragma unroll
        for (int e = 0; e < 64; ++e) {
            const float* wp = W + (size_t)e * DDIM + k;
            double a = lg[e];
#pragma unroll
            for (int j = 0; j < 4; ++j) a = fma(xd[j], (double)wp[j], a);
            lg[e] = a;
        }
    }
    unsigned long long selm = 0ull;
    double vals[TOPK]; int idx[TOPK];
#pragma unroll
    for (int i = 0; i < TOPK; ++i) {
        double m = -DBL_MAX; int mi = 0;
#pragma unroll
        for (int e = 0; e < 64; ++e) {
            bool gt = !((selm >> e) & 1ull) && (lg[e] > m);
            m = gt ? lg[e] : m; mi = gt ? e : mi;
        }
        vals[i] = m; idx[i] = mi; selm |= (1ull << mi);
    }
    double ssum = 0.0;
#pragma unroll
    for (int i = 0; i < TOPK; ++i) ssum += exp(vals[i] - vals[0]);
    double inv = 1.0 / ssum;
#pragma unroll
    for (int e = 0; e < 64; ++e)
        outp[(size_t)row * NEXP + e] =
            ((selm >> e) & 1ull) ? (float)(exp(lg[e] - vals[0]) * inv) : 0.0f;
#pragma unroll
    for (int i = 0; i < TOPK; ++i)
        outi[(size_t)row * TOPK + i] = (float)idx[i];
}

// ---------------------------------------------------------------------------
extern "C" void kernel_launch(void* const* d_in, const int* in_sizes, int n_in,
                              void* d_out, int out_size, void* d_ws, size_t ws_size,
                              hipStream_t stream) {
    (void)in_sizes; (void)n_in; (void)out_size;
    const float* x = (const float*)d_in[0];
    const float* W = (const float*)d_in[1];
    const float* b = (const float*)d_in[2];

    float* outp = (float*)d_out;
    float* outi = outp + (size_t)NROWS * NEXP;

    const size_t wd_bytes  = sizeof(double) * (size_t)NEXP * DDIM;          // 2 MB
    const size_t cnt_off   = wd_bytes;
    const size_t list_off  = cnt_off + 256;
    const size_t part_off  = list_off + (size_t)NROWS * sizeof(int);
    const size_t need      = part_off + (size_t)KSPLIT * NROWS * NEXP * sizeof(float);

    if (ws_size >= need) {
        double* Wd   = (double*)d_ws;
        int*    cnt  = (int*)((char*)d_ws + cnt_off);
        int*    list = (int*)((char*)d_ws + list_off);
        float*  part = (float*)((char*)d_ws + part_off);

        prep_kernel<<<(NEXP * DDIM) / 256, 256, 0, stream>>>(W, Wd, cnt);
        gate_kernel<<<(NROWS / RB) * KSPLIT, 256, 0, stream>>>(x, W, part);
        reduce_kernel<<<NROWS / 4, 256, 0, stream>>>(part, b, outp, outi, cnt, list);
        fix_kernel<<<1024, 64, 0, stream>>>(x, Wd, b, outp, outi, cnt, list);
    } else {
        fallback_kernel<<<NROWS / 64, 64, 0, stream>>>(x, W, b, outp, outi);
    }
}